// Round 1
// baseline (258.473 us; speedup 1.0000x reference)
//
#include <hip/hip_runtime.h>
#include <math.h>

// Shapes (fixed by the reference)
#define Bb   16
#define Ss   2048
#define Rr   196
#define Hh   768
#define Mtot (Bb * Rr)      // 3136 rows of img
#define NT   (Hh / 64)      // 12 n-tiles in K1

// ---------------------------------------------------------------------------
// K1: C = img(M x K=768) * W_img^T(N=768 x K=768), fused epilogue:
//     part[n_tile][m] = sum_{n in tile} tanh(C[m,n]) * w2[n]
// grid (M/64, N/64) = (49, 12), block 256, 64x64x16 tiles, 4x4 microtile.
// ---------------------------------------------------------------------------
__global__ __launch_bounds__(256) void k1_gemm_tanh(
    const float* __restrict__ A,      // img, M x 768 row-major
    const float* __restrict__ W,      // W_img, 768 x 768 row-major
    const float* __restrict__ w_att,  // 2H; w2 = w_att + 768
    float* __restrict__ part)         // NT x Mtot
{
    const int m0 = blockIdx.x * 64;
    const int n0 = blockIdx.y * 64;
    const int t  = threadIdx.x;

    __shared__ float As[16][68];   // k-major, padded (stride 68 keeps 16B align)
    __shared__ float Bs[16][68];

    const int lr = t >> 2;   // 0..63 : tile row for staging
    const int lq = t & 3;    // 0..3  : which float4 of the 16-wide k strip
    const int tm = t & 15;   // 0..15 : micro-tile row group
    const int tn = t >> 4;   // 0..15 : micro-tile col group

    float acc[4][4] = {};

    for (int k0 = 0; k0 < 768; k0 += 16) {
        float4 a4 = *(const float4*)&A[(size_t)(m0 + lr) * 768 + k0 + 4 * lq];
        float4 b4 = *(const float4*)&W[(size_t)(n0 + lr) * 768 + k0 + 4 * lq];
        __syncthreads();   // previous iteration's reads complete
        As[4 * lq + 0][lr] = a4.x;
        As[4 * lq + 1][lr] = a4.y;
        As[4 * lq + 2][lr] = a4.z;
        As[4 * lq + 3][lr] = a4.w;
        Bs[4 * lq + 0][lr] = b4.x;
        Bs[4 * lq + 1][lr] = b4.y;
        Bs[4 * lq + 2][lr] = b4.z;
        Bs[4 * lq + 3][lr] = b4.w;
        __syncthreads();
#pragma unroll
        for (int k = 0; k < 16; ++k) {
            float4 av = *(const float4*)&As[k][4 * tm];
            float4 bv = *(const float4*)&Bs[k][4 * tn];
            float am[4] = {av.x, av.y, av.z, av.w};
            float bn[4] = {bv.x, bv.y, bv.z, bv.w};
#pragma unroll
            for (int i = 0; i < 4; ++i)
#pragma unroll
                for (int j = 0; j < 4; ++j)
                    acc[i][j] = fmaf(am[i], bn[j], acc[i][j]);
        }
    }

    // Epilogue: tanh * w2, reduce over the 64 columns of this n-tile.
    const float* w2 = w_att + Hh;
    float wj[4];
#pragma unroll
    for (int j = 0; j < 4; ++j) wj[j] = w2[n0 + 4 * tn + j];

    __shared__ float red[64][17];
#pragma unroll
    for (int i = 0; i < 4; ++i) {
        float s = 0.f;
#pragma unroll
        for (int j = 0; j < 4; ++j) s += tanhf(acc[i][j]) * wj[j];
        red[4 * tm + i][tn] = s;
    }
    __syncthreads();
    if (t < 64) {
        float s = 0.f;
#pragma unroll
        for (int q = 0; q < 16; ++q) s += red[t][q];
        part[blockIdx.y * Mtot + m0 + t] = s;
    }
}

// ---------------------------------------------------------------------------
// K2: per batch b: is[r] = sum_nt part[nt][b*Rr+r]; p = softmax(is);
//     v[b,h] = sum_r p[r] * img[b,r,h]
// grid (Bb, 4): each y-block recomputes softmax (cheap) and handles 192 h's.
// ---------------------------------------------------------------------------
__global__ __launch_bounds__(256) void k2_softmax_v(
    const float* __restrict__ part,
    const float* __restrict__ img,
    float* __restrict__ v)
{
    const int b = blockIdx.x;
    const int t = threadIdx.x;

    __shared__ float p[Rr];
    __shared__ float redbuf[256];

    float myv = -INFINITY;
    if (t < Rr) {
        float s = 0.f;
#pragma unroll
        for (int nt = 0; nt < NT; ++nt) s += part[nt * Mtot + b * Rr + t];
        p[t] = s;
        myv = s;
    }
    // block max
    redbuf[t] = myv;
    __syncthreads();
    for (int off = 128; off > 0; off >>= 1) {
        if (t < off) redbuf[t] = fmaxf(redbuf[t], redbuf[t + off]);
        __syncthreads();
    }
    const float mx = redbuf[0];
    __syncthreads();

    float e = 0.f;
    if (t < Rr) {
        e = expf(p[t] - mx);
        p[t] = e;
    }
    redbuf[t] = e;
    __syncthreads();
    for (int off = 128; off > 0; off >>= 1) {
        if (t < off) redbuf[t] += redbuf[t + off];
        __syncthreads();
    }
    const float inv = 1.f / redbuf[0];
    __syncthreads();
    if (t < Rr) p[t] *= inv;
    __syncthreads();

    // weighted sum of img rows; this block handles h in [h0, h0+192)
    const int h0 = blockIdx.y * 192;
    if (t < 192) {
        const int h = h0 + t;
        float s = 0.f;
        const float* imgb = img + (size_t)b * Rr * Hh + h;
#pragma unroll 4
        for (int r = 0; r < Rr; ++r)
            s = fmaf(p[r], imgb[(size_t)r * Hh], s);
        v[b * Hh + h] = s;
    }
}

// ---------------------------------------------------------------------------
// K3: out[b,s,:] = v[b,:]  — 100 MB of float4 stores.
// ---------------------------------------------------------------------------
__global__ __launch_bounds__(256) void k3_bcast(
    const float4* __restrict__ v4,
    float4* __restrict__ out)
{
    const int gid   = blockIdx.x * 256 + threadIdx.x;   // < 6291456
    const int per_b = Ss * (Hh / 4);                    // 393216 float4 per batch
    const int b     = gid / per_b;
    const int h4    = gid % (Hh / 4);                   // 0..191
    out[gid] = v4[b * (Hh / 4) + h4];
}

// ---------------------------------------------------------------------------
extern "C" void kernel_launch(void* const* d_in, const int* in_sizes, int n_in,
                              void* d_out, int out_size, void* d_ws, size_t ws_size,
                              hipStream_t stream)
{
    // Input order: text_features, img_features, W_text, b_text, W_img, w_att, b_att
    const float* img   = (const float*)d_in[1];
    const float* W_img = (const float*)d_in[4];
    const float* w_att = (const float*)d_in[5];
    // text_features / W_text / b_text / b_att are mathematically dead:
    // softmax over r is invariant to the per-(b,s) text score and to b_att.

    float* part = (float*)d_ws;            // NT * Mtot floats   (150528 B)
    float* v    = part + NT * Mtot;        // Bb * Hh floats     (49152 B)
    float* out  = (float*)d_out;

    dim3 g1(Mtot / 64, Hh / 64);           // (49, 12)
    k1_gemm_tanh<<<g1, 256, 0, stream>>>(img, W_img, w_att, part);

    k2_softmax_v<<<dim3(Bb, 4), 256, 0, stream>>>(part, img, v);

    const int total4 = Bb * Ss * (Hh / 4); // 6291456
    k3_bcast<<<total4 / 256, 256, 0, stream>>>((const float4*)v, (float4*)out);
}

// Round 3
// 193.994 us; speedup vs baseline: 1.3324x; 1.3324x over previous
//
#include <hip/hip_runtime.h>
#include <math.h>

// Shapes (fixed by the reference)
#define Bb   16
#define Ss   2048
#define Rr   196
#define Hh   768
#define Mtot (Bb * Rr)      // 3136 rows of img
#define NT   (Hh / 64)      // 12 n-tiles in K1
#define LDA  72             // LDS row stride in bf16 elems (64 + 8 pad; keeps 16B align)

typedef __attribute__((ext_vector_type(8))) short short8;
typedef __attribute__((ext_vector_type(4))) short short4v;
typedef __attribute__((ext_vector_type(4))) float f32x4;

__device__ inline short f2bf(float f) {
    unsigned u = __builtin_bit_cast(unsigned, f);
    u += 0x7fff + ((u >> 16) & 1);          // round-to-nearest-even
    return (short)(u >> 16);
}

// ---------------------------------------------------------------------------
// K0: fp32 -> bf16 conversion of img (602112 float4) and W_img (147456 float4)
// ---------------------------------------------------------------------------
__global__ __launch_bounds__(256) void k0_cvt(
    const f32x4* __restrict__ a, short4v* __restrict__ da, int na4,
    const f32x4* __restrict__ b, short4v* __restrict__ db)
{
    int gid = blockIdx.x * 256 + threadIdx.x;
    const f32x4* s;
    short4v* d;
    int i;
    if (gid < na4) { s = a; d = da; i = gid; }
    else           { s = b; d = db; i = gid - na4; }
    f32x4 x = s[i];
    short4v o;
    o.x = f2bf(x.x); o.y = f2bf(x.y); o.z = f2bf(x.z); o.w = f2bf(x.w);
    d[i] = o;
}

// ---------------------------------------------------------------------------
// K1: pre = img (M x K) * W^T (N x K), bf16 MFMA 16x16x32, fused epilogue
//     part[nt][m] = sum_{n in 64-tile} tanh(pre[m,n]) * w2[n]
// grid (49, 12), block 256 (4 waves), tile 64x64, BK=64.
// ---------------------------------------------------------------------------
template <bool FROM_F32>
__global__ __launch_bounds__(256) void k1_mfma(
    const void* __restrict__ Ap, const void* __restrict__ Bp,
    const float* __restrict__ w_att, float* __restrict__ part)
{
    const int m0   = blockIdx.x * 64;
    const int n0   = blockIdx.y * 64;
    const int t    = threadIdx.x;
    const int lane = t & 63;
    const int wv   = t >> 6;
    const int wm   = (wv & 1) * 32;
    const int wn   = (wv >> 1) * 32;
    const int col  = lane & 15;
    const int quad = lane >> 4;

    __shared__ short As[64 * LDA];
    __shared__ short Bs[64 * LDA];
    __shared__ float red[64][2];

    f32x4 acc[2][2] = {};   // [mi][ni]

    const int sm = t >> 2;  // staging row 0..63
    const int sq = t & 3;   // staging k-quarter 0..3

    for (int k0 = 0; k0 < Hh; k0 += 64) {
        short8 areg[2], breg[2];
        if (FROM_F32) {
            const float* A = (const float*)Ap;
            const float* B = (const float*)Bp;
#pragma unroll
            for (int j = 0; j < 2; ++j) {
                float4 lo = *(const float4*)&A[(size_t)(m0 + sm) * Hh + k0 + sq * 16 + j * 8];
                float4 hi = *(const float4*)&A[(size_t)(m0 + sm) * Hh + k0 + sq * 16 + j * 8 + 4];
                areg[j][0] = f2bf(lo.x); areg[j][1] = f2bf(lo.y);
                areg[j][2] = f2bf(lo.z); areg[j][3] = f2bf(lo.w);
                areg[j][4] = f2bf(hi.x); areg[j][5] = f2bf(hi.y);
                areg[j][6] = f2bf(hi.z); areg[j][7] = f2bf(hi.w);
                lo = *(const float4*)&B[(size_t)(n0 + sm) * Hh + k0 + sq * 16 + j * 8];
                hi = *(const float4*)&B[(size_t)(n0 + sm) * Hh + k0 + sq * 16 + j * 8 + 4];
                breg[j][0] = f2bf(lo.x); breg[j][1] = f2bf(lo.y);
                breg[j][2] = f2bf(lo.z); breg[j][3] = f2bf(lo.w);
                breg[j][4] = f2bf(hi.x); breg[j][5] = f2bf(hi.y);
                breg[j][6] = f2bf(hi.z); breg[j][7] = f2bf(hi.w);
            }
        } else {
            const short* A = (const short*)Ap;
            const short* B = (const short*)Bp;
#pragma unroll
            for (int j = 0; j < 2; ++j) {
                areg[j] = *(const short8*)&A[(size_t)(m0 + sm) * Hh + k0 + sq * 16 + j * 8];
                breg[j] = *(const short8*)&B[(size_t)(n0 + sm) * Hh + k0 + sq * 16 + j * 8];
            }
        }
        __syncthreads();   // previous iteration's frag reads complete
#pragma unroll
        for (int j = 0; j < 2; ++j) {
            *(short8*)&As[sm * LDA + sq * 16 + j * 8] = areg[j];
            *(short8*)&Bs[sm * LDA + sq * 16 + j * 8] = breg[j];
        }
        __syncthreads();
#pragma unroll
        for (int kk = 0; kk < 64; kk += 32) {
            short8 a0 = *(const short8*)&As[(wm +      col) * LDA + kk + quad * 8];
            short8 a1 = *(const short8*)&As[(wm + 16 + col) * LDA + kk + quad * 8];
            short8 b0 = *(const short8*)&Bs[(wn +      col) * LDA + kk + quad * 8];
            short8 b1 = *(const short8*)&Bs[(wn + 16 + col) * LDA + kk + quad * 8];
            acc[0][0] = __builtin_amdgcn_mfma_f32_16x16x32_bf16(a0, b0, acc[0][0], 0, 0, 0);
            acc[0][1] = __builtin_amdgcn_mfma_f32_16x16x32_bf16(a0, b1, acc[0][1], 0, 0, 0);
            acc[1][0] = __builtin_amdgcn_mfma_f32_16x16x32_bf16(a1, b0, acc[1][0], 0, 0, 0);
            acc[1][1] = __builtin_amdgcn_mfma_f32_16x16x32_bf16(a1, b1, acc[1][1], 0, 0, 0);
        }
    }

    // Epilogue: tanh * w2, reduce over this block's 64 n-columns.
    const float* w2 = w_att + Hh;
    float w2v0 = w2[n0 + wn + col];
    float w2v1 = w2[n0 + wn + 16 + col];

#pragma unroll
    for (int mi = 0; mi < 2; ++mi) {
#pragma unroll
        for (int r = 0; r < 4; ++r) {
            float s = tanhf(acc[mi][0][r]) * w2v0 + tanhf(acc[mi][1][r]) * w2v1;
            s += __shfl_xor(s, 1, 64);
            s += __shfl_xor(s, 2, 64);
            s += __shfl_xor(s, 4, 64);
            s += __shfl_xor(s, 8, 64);
            if (col == 0)
                red[wm + mi * 16 + quad * 4 + r][wn >> 5] = s;
        }
    }
    __syncthreads();
    if (t < 64)
        part[blockIdx.y * Mtot + m0 + t] = red[t][0] + red[t][1];
}

// ---------------------------------------------------------------------------
// K2: per batch b: scores[r] = sum_nt part[nt][b*Rr+r]; p = softmax(scores);
//     v[b,h] = sum_r p[r] * img[b,r,h].   grid (16, 12).
// ---------------------------------------------------------------------------
__global__ __launch_bounds__(256) void k2_softmax_v(
    const float* __restrict__ part,
    const float* __restrict__ img,
    float* __restrict__ v)
{
    const int b = blockIdx.x;
    const int t = threadIdx.x;

    __shared__ float p[Rr];
    __shared__ float redbuf[256];
    __shared__ float a2[4][65];

    float myv = -INFINITY;
    if (t < Rr) {
        float s = 0.f;
#pragma unroll
        for (int nt = 0; nt < NT; ++nt) s += part[nt * Mtot + b * Rr + t];
        p[t] = s;
        myv = s;
    }
    redbuf[t] = myv;
    __syncthreads();
    for (int off = 128; off > 0; off >>= 1) {
        if (t < off) redbuf[t] = fmaxf(redbuf[t], redbuf[t + off]);
        __syncthreads();
    }
    const float mx = redbuf[0];
    __syncthreads();

    float e = 0.f;
    if (t < Rr) e = expf(p[t] - mx);
    redbuf[t] = e;
    __syncthreads();
    for (int off = 128; off > 0; off >>= 1) {
        if (t < off) redbuf[t] += redbuf[t + off];
        __syncthreads();
    }
    const float inv = 1.f / redbuf[0];
    __syncthreads();
    if (t < Rr) p[t] = e * inv;
    __syncthreads();

    // weighted sum over r, split in 4 groups of 49
    const int h  = blockIdx.y * 64 + (t & 63);
    const int rg = t >> 6;
    const float* imgb = img + (size_t)b * Rr * Hh + h;
    float s = 0.f;
#pragma unroll 7
    for (int r = rg * 49; r < rg * 49 + 49; ++r)
        s = fmaf(p[r], imgb[(size_t)r * Hh], s);
    a2[rg][t & 63] = s;
    __syncthreads();
    if (t < 64)
        v[b * Hh + blockIdx.y * 64 + t] = a2[0][t] + a2[1][t] + a2[2][t] + a2[3][t];
}

// ---------------------------------------------------------------------------
// K3: out[b,s,:] = v[b,:]  — 100 MB of nontemporal vector stores.
// ---------------------------------------------------------------------------
__global__ __launch_bounds__(256) void k3_bcast(
    const f32x4* __restrict__ v4,
    f32x4* __restrict__ out)
{
    const int gid   = blockIdx.x * 256 + threadIdx.x;   // < 6291456
    const int per_b = Ss * (Hh / 4);                    // 393216 f32x4 per batch
    const int b     = gid / per_b;
    const int h4    = gid % (Hh / 4);                   // 0..191
    f32x4 val = v4[b * (Hh / 4) + h4];
    __builtin_nontemporal_store(val, &out[gid]);
}

// ---------------------------------------------------------------------------
extern "C" void kernel_launch(void* const* d_in, const int* in_sizes, int n_in,
                              void* d_out, int out_size, void* d_ws, size_t ws_size,
                              hipStream_t stream)
{
    // Input order: text_features, img_features, W_text, b_text, W_img, w_att, b_att
    const float* img   = (const float*)d_in[1];
    const float* W_img = (const float*)d_in[4];
    const float* w_att = (const float*)d_in[5];
    // text_features / W_text / b_text / b_att are mathematically dead:
    // softmax over r is invariant to the per-(b,s) text score and to b_att.

    float* part = (float*)d_ws;                  // NT*Mtot floats   = 150528 B
    float* v    = part + NT * Mtot;              // Bb*Hh floats     =  49152 B
    size_t off  = ((size_t)(NT * Mtot + Bb * Hh) * 4 + 15) & ~(size_t)15;
    short* imgbf = (short*)((char*)d_ws + off);                  // 4816896 B
    short* Wbf   = imgbf + (size_t)Mtot * Hh;                    // 1179648 B
    const size_t need = off + ((size_t)Mtot * Hh + (size_t)Hh * Hh) * 2;

    float* out = (float*)d_out;
    const bool usebf = (ws_size >= need);        // constant across calls -> graph-safe

    if (usebf) {
        const int na4 = (Mtot * Hh) / 4;         // 602112
        const int nb4 = (Hh * Hh) / 4;           // 147456
        k0_cvt<<<(na4 + nb4) / 256, 256, 0, stream>>>(
            (const f32x4*)img, (short4v*)imgbf, na4,
            (const f32x4*)W_img, (short4v*)Wbf);
        k1_mfma<false><<<dim3(Mtot / 64, NT), 256, 0, stream>>>(imgbf, Wbf, w_att, part);
    } else {
        k1_mfma<true><<<dim3(Mtot / 64, NT), 256, 0, stream>>>(img, W_img, w_att, part);
    }

    k2_softmax_v<<<dim3(Bb, NT), 256, 0, stream>>>(part, img, v);

    const int total4 = Bb * Ss * (Hh / 4);       // 6291456
    k3_bcast<<<total4 / 256, 256, 0, stream>>>((const f32x4*)v, (f32x4*)out);
}